// Round 8
// baseline (234.995 us; speedup 1.0000x reference)
//
#include <hip/hip_runtime.h>
#include <hip/hip_bf16.h>
#include <hip/hip_fp16.h>

// ---------------------------------------------------------------------------
// GCN 3-layer forward.
//  - Layers 1-2 GEMM: bf16 MFMA (16x16x32), fp32 accum.
//  - Layer 3 GEMM: fp32 vector (error insurance on the output layer).
//  - Aggregation: CSR-by-dst gather of bf16 rows, fp32 accum, 2 nodes/wave.
//  - Streaming one-touch data (edge lists, ep metadata, agg outputs) uses
//    NON-TEMPORAL loads/stores so the XCD L2s keep the hot data resident:
//    k_fill's ep slice (fixes partial-line writeback amplification) and the
//    aggregations' gathered t array.
//  - Edge record: u32 {fp16 norm | u16 src}. Rows padded to x8, pad = 0.
//  - CSR fill dst-partitioned 8 ways for XCD-local writes.
// ---------------------------------------------------------------------------

typedef __attribute__((ext_vector_type(8))) short s16x8;
typedef __attribute__((ext_vector_type(8))) unsigned short u16x8;
typedef __attribute__((ext_vector_type(4))) float f32x4;
typedef __attribute__((ext_vector_type(4))) uint u32x4;

__device__ __forceinline__ float bfu_lo(uint v) { return __uint_as_float(v << 16); }
__device__ __forceinline__ float bfu_hi(uint v) { return __uint_as_float(v & 0xffff0000u); }
__device__ __forceinline__ float dec_norm(uint m) {
    return __half2float(__ushort_as_half((ushort)(m >> 16)));
}
__device__ __forceinline__ ushort bf16_bits(float f) {
    union { __hip_bfloat16 h; ushort u; } x;
    x.h = __float2bfloat16(f);
    return x.u;
}
__device__ __forceinline__ u32x4 nt_load4(const uint* p) {
    return __builtin_nontemporal_load((const u32x4*)p);
}

// ---------------- CSR build ----------------

__global__ void k_init(int* __restrict__ deg, int n,
                       uint4* __restrict__ ep4, int cap4) {
    int i = blockIdx.x * blockDim.x + threadIdx.x;
    if (i < n) deg[i] = 1;
    if (i < cap4) ep4[i] = make_uint4(0u, 0u, 0u, 0u);
}

__global__ void k_hist(const int* __restrict__ dst, int E, int* __restrict__ deg) {
    int e = blockIdx.x * blockDim.x + threadIdx.x;
    if (e < E) atomicAdd(&deg[__builtin_nontemporal_load(dst + e)], 1);
}

__global__ void k_scan_block(const int* __restrict__ deg, int* __restrict__ offs,
                             int* __restrict__ bsum, float* __restrict__ dinv, int n) {
    __shared__ int sm[256];
    int tid = threadIdx.x;
    int i = blockIdx.x * 256 + tid;
    int v = (i < n) ? deg[i] : 0;
    int pv = (i < n) ? ((v + 7) & ~7) : 0;   // pad rows to x8
    if (i < n) dinv[i] = rsqrtf((float)v);
    sm[tid] = pv;
    __syncthreads();
    for (int off = 1; off < 256; off <<= 1) {
        int t = (tid >= off) ? sm[tid - off] : 0;
        __syncthreads();
        sm[tid] += t;
        __syncthreads();
    }
    if (i < n) offs[i] = sm[tid] - pv;
    if (tid == 255) bsum[blockIdx.x] = sm[255];
}

__global__ void k_scan_bsum(int* __restrict__ bsum, int nb, int* __restrict__ offs, int n) {
    __shared__ int sm[256];
    int tid = threadIdx.x;
    int v = (tid < nb) ? bsum[tid] : 0;
    sm[tid] = v;
    __syncthreads();
    for (int off = 1; off < 256; off <<= 1) {
        int t = (tid >= off) ? sm[tid - off] : 0;
        __syncthreads();
        sm[tid] += t;
        __syncthreads();
    }
    if (tid < nb) bsum[tid] = sm[tid] - v;
    if (tid == 255) offs[n] = sm[255];
}

__global__ void k_add_bsum(int* __restrict__ offs, const int* __restrict__ bsum,
                           int* __restrict__ cursor, int n) {
    int i = blockIdx.x * blockDim.x + threadIdx.x;
    if (i < n) {
        int o = offs[i] + bsum[i >> 8];
        offs[i] = o;
        cursor[i] = o;
    }
}

// dst-partitioned CSR fill; streaming edge reads are NON-TEMPORAL so the
// ep slice + cursor stay L2-resident and lines fill before writeback.
#define FILL_SPAN 4096
__global__ __launch_bounds__(256) void k_fill(const int* __restrict__ src,
                                              const int* __restrict__ dst,
                                              int E, int n, int* __restrict__ cursor,
                                              const float* __restrict__ dinv,
                                              uint* __restrict__ ep) {
    const int part = blockIdx.x & 7;
    const int chunk = blockIdx.x >> 3;
    const int tot = E + n;
    const int base = chunk * FILL_SPAN;
    const int end = min(base + FILL_SPAN, tot);
    const int lo = (int)(((long long)n * part) >> 3);
    const int hi = (int)(((long long)n * (part + 1)) >> 3);
    for (int e = base + (int)threadIdx.x; e < end; e += 256) {
        int d = (e < E) ? __builtin_nontemporal_load(dst + e) : (e - E);
        if (d >= lo && d < hi) {
            int s = (e < E) ? __builtin_nontemporal_load(src + e) : (e - E);
            int pos = atomicAdd(&cursor[d], 1);
            uint hb = (uint)__half_as_ushort(__float2half(dinv[s] * dinv[d]));
            ep[pos] = (hb << 16) | (uint)s;
        }
    }
}

// ---------------- W transpose+quantize (once per launch) ----------------
__global__ void k_transW(const float* __restrict__ W1, const float* __restrict__ W2,
                         ushort* __restrict__ Wt1, ushort* __restrict__ Wt2) {
    int i = blockIdx.x * 256 + threadIdx.x;
    if (i < 128 * 128) {
        int r = i >> 7, c = i & 127;
        Wt1[c * 128 + r] = bf16_bits(W1[i]);
        Wt2[c * 128 + r] = bf16_bits(W2[i]);
    }
}

// ---------------- MFMA GEMM (OUT=128): T = A @ W, bf16 in, bf16 out -------
template <bool ABF16>
__global__ __launch_bounds__(256) void k_gemm_mfma(const void* __restrict__ Ain,
                                                   const ushort* __restrict__ Wt,
                                                   __hip_bfloat16* __restrict__ T, int n) {
    __shared__ ushort As[64][136];
    __shared__ ushort Ws[128][136];
    const int tid = threadIdx.x;
    const int wave = tid >> 6, lane = tid & 63;
    const int m0 = blockIdx.x * 64;

#pragma unroll
    for (int it = 0; it < 8; ++it) {
        int idx = it * 256 + tid;
        int r = idx >> 4;
        int c8 = (idx & 15) << 3;
        *(u16x8*)&Ws[r][c8] = *(const u16x8*)(Wt + r * 128 + c8);
    }
    if constexpr (ABF16) {
        const ushort* A = (const ushort*)Ain;
#pragma unroll
        for (int it = 0; it < 4; ++it) {
            int idx = it * 256 + tid;
            int r = idx >> 4;
            int c8 = (idx & 15) << 3;
            u16x8 v = {0, 0, 0, 0, 0, 0, 0, 0};
            if (m0 + r < n) v = *(const u16x8*)(A + (size_t)(m0 + r) * 128 + c8);
            *(u16x8*)&As[r][c8] = v;
        }
    } else {
        const float* A = (const float*)Ain;
#pragma unroll
        for (int it = 0; it < 8; ++it) {
            int idx = it * 256 + tid;
            int r = idx >> 5;
            int c4 = (idx & 31) << 2;
            float4 v = make_float4(0.f, 0.f, 0.f, 0.f);
            if (m0 + r < n) v = *(const float4*)(A + (size_t)(m0 + r) * 128 + c4);
            As[r][c4 + 0] = bf16_bits(v.x);
            As[r][c4 + 1] = bf16_bits(v.y);
            As[r][c4 + 2] = bf16_bits(v.z);
            As[r][c4 + 3] = bf16_bits(v.w);
        }
    }
    __syncthreads();

    const int lrow = lane & 15;
    const int kgrp = lane >> 4;

    s16x8 a[4];
#pragma unroll
    for (int kk = 0; kk < 4; ++kk)
        a[kk] = *(const s16x8*)&As[wave * 16 + lrow][kk * 32 + kgrp * 8];

    f32x4 acc[8];
#pragma unroll
    for (int nt = 0; nt < 8; ++nt) {
        f32x4 c = {0.f, 0.f, 0.f, 0.f};
#pragma unroll
        for (int kk = 0; kk < 4; ++kk) {
            s16x8 b = *(const s16x8*)&Ws[nt * 16 + lrow][kk * 32 + kgrp * 8];
            c = __builtin_amdgcn_mfma_f32_16x16x32_bf16(a[kk], b, c, 0, 0, 0);
        }
        acc[nt] = c;
    }

    ushort* To = (ushort*)T;
#pragma unroll
    for (int j = 0; j < 4; ++j) {
        int row = m0 + wave * 16 + kgrp * 4 + j;
        if (row < n) {
#pragma unroll
            for (int nt = 0; nt < 8; ++nt)
                To[(size_t)row * 128 + nt * 16 + lrow] = bf16_bits(acc[nt][j]);
        }
    }
}

// ---------------- fp32 vector GEMM (OUT=64, layer 3), A bf16 --------------
__global__ __launch_bounds__(256) void k_gemm64(const ushort* __restrict__ Aq,
                                                const float* __restrict__ W,
                                                __hip_bfloat16* __restrict__ T, int n) {
    __shared__ float As[32][68];
    __shared__ float Bs[32][68];
    const int tid = threadIdx.x;
    const int tx = tid & 15, ty = tid >> 4;
    const int m0 = blockIdx.x * 64;

    float acc[4][4] = {};

    for (int k0 = 0; k0 < 128; k0 += 32) {
#pragma unroll
        for (int it = 0; it < 2; ++it) {
            int idx = it * 256 + tid;
            int r = idx >> 3;
            int c4 = (idx & 7) << 2;
            float4 v = make_float4(0.f, 0.f, 0.f, 0.f);
            if (m0 + r < n) {
                ushort4 u = *(const ushort4*)(Aq + (size_t)(m0 + r) * 128 + k0 + c4);
                v.x = __uint_as_float((uint)u.x << 16);
                v.y = __uint_as_float((uint)u.y << 16);
                v.z = __uint_as_float((uint)u.z << 16);
                v.w = __uint_as_float((uint)u.w << 16);
            }
            As[c4 + 0][r] = v.x;
            As[c4 + 1][r] = v.y;
            As[c4 + 2][r] = v.z;
            As[c4 + 3][r] = v.w;
        }
#pragma unroll
        for (int it = 0; it < 2; ++it) {
            int idx = it * 256 + tid;
            int kk = idx >> 4;
            int c4 = (idx & 15) << 2;
            *(float4*)&Bs[kk][c4] = *(const float4*)(W + (size_t)(k0 + kk) * 64 + c4);
        }
        __syncthreads();

#pragma unroll
        for (int k = 0; k < 32; ++k) {
            float4 a = *(const float4*)&As[k][ty * 4];
            float4 b0 = *(const float4*)&Bs[k][tx * 4];
            float av[4] = {a.x, a.y, a.z, a.w};
#pragma unroll
            for (int i = 0; i < 4; ++i) {
                acc[i][0] += av[i] * b0.x;
                acc[i][1] += av[i] * b0.y;
                acc[i][2] += av[i] * b0.z;
                acc[i][3] += av[i] * b0.w;
            }
        }
        __syncthreads();
    }

#pragma unroll
    for (int i = 0; i < 4; ++i) {
        int r = m0 + ty * 4 + i;
        if (r < n) {
            union { ushort h[4]; uint2 u; } p;
#pragma unroll
            for (int j = 0; j < 4; ++j) p.h[j] = bf16_bits(acc[i][j]);
            *(uint2*)((ushort*)T + (size_t)r * 64 + tx * 4) = p.u;
        }
    }
}

// ---------------- Aggregation: 2 nodes per wave, 16 gathers in flight -----
// ep metadata reads and h/out writes are NON-TEMPORAL (one-touch streams);
// the gathered t array is what we want the XCD L2s to hold.
template <bool RELU>
__global__ __launch_bounds__(256) void k_agg128(const __hip_bfloat16* __restrict__ T,
                                                const int* __restrict__ offs,
                                                const uint* __restrict__ ep,
                                                const float* __restrict__ bias,
                                                uint* __restrict__ outq, int n) {
    int pr = blockIdx.x * 4 + (threadIdx.x >> 6);
    int lane = threadIdx.x & 63;
    int w0 = pr * 2;
    if (w0 >= n) return;
    int w1 = w0 + 1;
    bool has1 = (w1 < n);
    int eA = offs[w0], endA = offs[w0 + 1];
    int eB = has1 ? offs[w1] : 0;
    int endB = has1 ? offs[w1 + 1] : 0;

    const uint* Tl = (const uint*)T + lane;
    const u32x4 z4 = {0u, 0u, 0u, 0u};
    float a0 = 0.f, a1 = 0.f, c0 = 0.f, c1 = 0.f;

    u32x4 mA0 = nt_load4(ep + eA);
    u32x4 mA1 = nt_load4(ep + eA + 4);
    u32x4 mB0 = z4, mB1 = z4;
    if (eB < endB) { mB0 = nt_load4(ep + eB); mB1 = nt_load4(ep + eB + 4); }

    for (;;) {
        uint rA0 = Tl[(size_t)(mA0.x & 0xffffu) * 64];
        uint rA1 = Tl[(size_t)(mA0.y & 0xffffu) * 64];
        uint rA2 = Tl[(size_t)(mA0.z & 0xffffu) * 64];
        uint rA3 = Tl[(size_t)(mA0.w & 0xffffu) * 64];
        uint rA4 = Tl[(size_t)(mA1.x & 0xffffu) * 64];
        uint rA5 = Tl[(size_t)(mA1.y & 0xffffu) * 64];
        uint rA6 = Tl[(size_t)(mA1.z & 0xffffu) * 64];
        uint rA7 = Tl[(size_t)(mA1.w & 0xffffu) * 64];
        uint rB0 = Tl[(size_t)(mB0.x & 0xffffu) * 64];
        uint rB1 = Tl[(size_t)(mB0.y & 0xffffu) * 64];
        uint rB2 = Tl[(size_t)(mB0.z & 0xffffu) * 64];
        uint rB3 = Tl[(size_t)(mB0.w & 0xffffu) * 64];
        uint rB4 = Tl[(size_t)(mB1.x & 0xffffu) * 64];
        uint rB5 = Tl[(size_t)(mB1.y & 0xffffu) * 64];
        uint rB6 = Tl[(size_t)(mB1.z & 0xffffu) * 64];
        uint rB7 = Tl[(size_t)(mB1.w & 0xffffu) * 64];
        float wA0 = dec_norm(mA0.x), wA1 = dec_norm(mA0.y);
        float wA2 = dec_norm(mA0.z), wA3 = dec_norm(mA0.w);
        float wA4 = dec_norm(mA1.x), wA5 = dec_norm(mA1.y);
        float wA6 = dec_norm(mA1.z), wA7 = dec_norm(mA1.w);
        float wB0 = dec_norm(mB0.x), wB1 = dec_norm(mB0.y);
        float wB2 = dec_norm(mB0.z), wB3 = dec_norm(mB0.w);
        float wB4 = dec_norm(mB1.x), wB5 = dec_norm(mB1.y);
        float wB6 = dec_norm(mB1.z), wB7 = dec_norm(mB1.w);
        eA += 8;
        eB += 8;
        bool moreA = (eA < endA), moreB = (eB < endB);
        if (moreA) { mA0 = nt_load4(ep + eA); mA1 = nt_load4(ep + eA + 4); }
        else       { mA0 = z4; mA1 = z4; }
        if (moreB) { mB0 = nt_load4(ep + eB); mB1 = nt_load4(ep + eB + 4); }
        else       { mB0 = z4; mB1 = z4; }
        a0 += wA0 * bfu_lo(rA0); a1 += wA0 * bfu_hi(rA0);
        a0 += wA1 * bfu_lo(rA1); a1 += wA1 * bfu_hi(rA1);
        a0 += wA2 * bfu_lo(rA2); a1 += wA2 * bfu_hi(rA2);
        a0 += wA3 * bfu_lo(rA3); a1 += wA3 * bfu_hi(rA3);
        a0 += wA4 * bfu_lo(rA4); a1 += wA4 * bfu_hi(rA4);
        a0 += wA5 * bfu_lo(rA5); a1 += wA5 * bfu_hi(rA5);
        a0 += wA6 * bfu_lo(rA6); a1 += wA6 * bfu_hi(rA6);
        a0 += wA7 * bfu_lo(rA7); a1 += wA7 * bfu_hi(rA7);
        c0 += wB0 * bfu_lo(rB0); c1 += wB0 * bfu_hi(rB0);
        c0 += wB1 * bfu_lo(rB1); c1 += wB1 * bfu_hi(rB1);
        c0 += wB2 * bfu_lo(rB2); c1 += wB2 * bfu_hi(rB2);
        c0 += wB3 * bfu_lo(rB3); c1 += wB3 * bfu_hi(rB3);
        c0 += wB4 * bfu_lo(rB4); c1 += wB4 * bfu_hi(rB4);
        c0 += wB5 * bfu_lo(rB5); c1 += wB5 * bfu_hi(rB5);
        c0 += wB6 * bfu_lo(rB6); c1 += wB6 * bfu_hi(rB6);
        c0 += wB7 * bfu_lo(rB7); c1 += wB7 * bfu_hi(rB7);
        if (!moreA && !moreB) break;
    }

    float2 b = *(const float2*)(bias + (lane << 1));
    a0 += b.x; a1 += b.y;
    if (RELU) { a0 = fmaxf(a0, 0.f); a1 = fmaxf(a1, 0.f); }
    __builtin_nontemporal_store(((uint)bf16_bits(a1) << 16) | (uint)bf16_bits(a0),
                                outq + (size_t)w0 * 64 + lane);
    if (has1) {
        c0 += b.x; c1 += b.y;
        if (RELU) { c0 = fmaxf(c0, 0.f); c1 = fmaxf(c1, 0.f); }
        __builtin_nontemporal_store(((uint)bf16_bits(c1) << 16) | (uint)bf16_bits(c0),
                                    outq + (size_t)w1 * 64 + lane);
    }
}

__global__ __launch_bounds__(256) void k_agg64(const __hip_bfloat16* __restrict__ T,
                                               const int* __restrict__ offs,
                                               const uint* __restrict__ ep,
                                               const float* __restrict__ bias,
                                               float* __restrict__ out, int n) {
    int pr = blockIdx.x * 4 + (threadIdx.x >> 6);
    int lane = threadIdx.x & 63;
    int w0 = pr * 2;
    if (w0 >= n) return;
    int w1 = w0 + 1;
    bool has1 = (w1 < n);
    int eA = offs[w0], endA = offs[w0 + 1];
    int eB = has1 ? offs[w1] : 0;
    int endB = has1 ? offs[w1 + 1] : 0;

    const ushort* Tl = (const ushort*)T + lane;
    const u32x4 z4 = {0u, 0u, 0u, 0u};
    float a0 = 0.f, c0 = 0.f;

    u32x4 mA0 = nt_load4(ep + eA);
    u32x4 mA1 = nt_load4(ep + eA + 4);
    u32x4 mB0 = z4, mB1 = z4;
    if (eB < endB) { mB0 = nt_load4(ep + eB); mB1 = nt_load4(ep + eB + 4); }

    for (;;) {
        float rA0 = __uint_as_float((uint)Tl[(size_t)(mA0.x & 0xffffu) * 64] << 16);
        float rA1 = __uint_as_float((uint)Tl[(size_t)(mA0.y & 0xffffu) * 64] << 16);
        float rA2 = __uint_as_float((uint)Tl[(size_t)(mA0.z & 0xffffu) * 64] << 16);
        float rA3 = __uint_as_float((uint)Tl[(size_t)(mA0.w & 0xffffu) * 64] << 16);
        float rA4 = __uint_as_float((uint)Tl[(size_t)(mA1.x & 0xffffu) * 64] << 16);
        float rA5 = __uint_as_float((uint)Tl[(size_t)(mA1.y & 0xffffu) * 64] << 16);
        float rA6 = __uint_as_float((uint)Tl[(size_t)(mA1.z & 0xffffu) * 64] << 16);
        float rA7 = __uint_as_float((uint)Tl[(size_t)(mA1.w & 0xffffu) * 64] << 16);
        float rB0 = __uint_as_float((uint)Tl[(size_t)(mB0.x & 0xffffu) * 64] << 16);
        float rB1 = __uint_as_float((uint)Tl[(size_t)(mB0.y & 0xffffu) * 64] << 16);
        float rB2 = __uint_as_float((uint)Tl[(size_t)(mB0.z & 0xffffu) * 64] << 16);
        float rB3 = __uint_as_float((uint)Tl[(size_t)(mB0.w & 0xffffu) * 64] << 16);
        float rB4 = __uint_as_float((uint)Tl[(size_t)(mB1.x & 0xffffu) * 64] << 16);
        float rB5 = __uint_as_float((uint)Tl[(size_t)(mB1.y & 0xffffu) * 64] << 16);
        float rB6 = __uint_as_float((uint)Tl[(size_t)(mB1.z & 0xffffu) * 64] << 16);
        float rB7 = __uint_as_float((uint)Tl[(size_t)(mB1.w & 0xffffu) * 64] << 16);
        float wA0 = dec_norm(mA0.x), wA1 = dec_norm(mA0.y);
        float wA2 = dec_norm(mA0.z), wA3 = dec_norm(mA0.w);
        float wA4 = dec_norm(mA1.x), wA5 = dec_norm(mA1.y);
        float wA6 = dec_norm(mA1.z), wA7 = dec_norm(mA1.w);
        float wB0 = dec_norm(mB0.x), wB1 = dec_norm(mB0.y);
        float wB2 = dec_norm(mB0.z), wB3 = dec_norm(mB0.w);
        float wB4 = dec_norm(mB1.x), wB5 = dec_norm(mB1.y);
        float wB6 = dec_norm(mB1.z), wB7 = dec_norm(mB1.w);
        eA += 8;
        eB += 8;
        bool moreA = (eA < endA), moreB = (eB < endB);
        if (moreA) { mA0 = nt_load4(ep + eA); mA1 = nt_load4(ep + eA + 4); }
        else       { mA0 = z4; mA1 = z4; }
        if (moreB) { mB0 = nt_load4(ep + eB); mB1 = nt_load4(ep + eB + 4); }
        else       { mB0 = z4; mB1 = z4; }
        a0 += wA0 * rA0 + wA1 * rA1 + wA2 * rA2 + wA3 * rA3;
        a0 += wA4 * rA4 + wA5 * rA5 + wA6 * rA6 + wA7 * rA7;
        c0 += wB0 * rB0 + wB1 * rB1 + wB2 * rB2 + wB3 * rB3;
        c0 += wB4 * rB4 + wB5 * rB5 + wB6 * rB6 + wB7 * rB7;
        if (!moreA && !moreB) break;
    }

    float bv = bias[lane];
    __builtin_nontemporal_store(a0 + bv, out + (size_t)w0 * 64 + lane);
    if (has1) __builtin_nontemporal_store(c0 + bv, out + (size_t)w1 * 64 + lane);
}

// ---------------------------------------------------------------------------

extern "C" void kernel_launch(void* const* d_in, const int* in_sizes, int n_in,
                              void* d_out, int out_size, void* d_ws, size_t ws_size,
                              hipStream_t stream) {
    const int n = in_sizes[0] / 128;   // 50000
    const int E = in_sizes[1] / 2;     // 800000

    const float* x  = (const float*)d_in[0];
    const int*   ei = (const int*)d_in[1];
    const float* W1 = (const float*)d_in[2];
    const float* b1 = (const float*)d_in[3];
    const float* W2 = (const float*)d_in[4];
    const float* b2 = (const float*)d_in[5];
    const float* W3 = (const float*)d_in[6];
    const float* b3 = (const float*)d_in[7];
    const int* src = ei;
    const int* dst = ei + E;
    float* out = (float*)d_out;

    const int cap = E + 8 * n;  // max padded slots

    char* w = (char*)d_ws;
    auto alloc = [&](size_t bytes) {
        char* p = w;
        w += (bytes + 255) & ~(size_t)255;
        return p;
    };
    int*    deg    = (int*)alloc((size_t)n * 4);
    int*    cursor = (int*)alloc((size_t)n * 4);
    int*    offs   = (int*)alloc((size_t)(n + 1) * 4);
    int*    bsum   = (int*)alloc(256 * 4);
    float*  dinv   = (float*)alloc((size_t)n * 4);
    uint*   ep     = (uint*)alloc((size_t)cap * 4);
    __hip_bfloat16* tA = (__hip_bfloat16*)alloc((size_t)n * 128 * 2); // gathered t
    uint*   hB     = (uint*)alloc((size_t)n * 64 * 4);                // h packed bf16x2
    ushort* Wt1    = (ushort*)alloc(128 * 128 * 2);
    ushort* Wt2    = (ushort*)alloc(128 * 128 * 2);

    const int nb = (n + 255) / 256;

    // ---- CSR build + weight prep ----
    const int cap4 = (cap + 3) / 4;
    k_init<<<(cap4 + 255) / 256, 256, 0, stream>>>(deg, n, (uint4*)ep, cap4);
    k_transW<<<64, 256, 0, stream>>>(W1, W2, Wt1, Wt2);
    k_hist<<<(E + 255) / 256, 256, 0, stream>>>(dst, E, deg);
    k_scan_block<<<nb, 256, 0, stream>>>(deg, offs, bsum, dinv, n);
    k_scan_bsum<<<1, 256, 0, stream>>>(bsum, nb, offs, n);
    k_add_bsum<<<nb, 256, 0, stream>>>(offs, bsum, cursor, n);
    const int nchunk = (E + n + FILL_SPAN - 1) / FILL_SPAN;
    k_fill<<<nchunk * 8, 256, 0, stream>>>(src, dst, E, n, cursor, dinv, ep);

    // ---- 3 GCN layers ----
    const int pair_blocks = ((n + 1) / 2 + 3) / 4;   // 2 nodes/wave, 4 waves/block
    const int gemm_blocks = (n + 63) / 64;

    k_gemm_mfma<false><<<gemm_blocks, 256, 0, stream>>>(x, Wt1, tA, n);
    k_agg128<true><<<pair_blocks, 256, 0, stream>>>(tA, offs, ep, b1, hB, n);

    k_gemm_mfma<true><<<gemm_blocks, 256, 0, stream>>>(hB, Wt2, tA, n);
    k_agg128<true><<<pair_blocks, 256, 0, stream>>>(tA, offs, ep, b2, hB, n);

    k_gemm64<<<gemm_blocks, 256, 0, stream>>>((const ushort*)hB, W3, tA, n);
    k_agg64<<<pair_blocks, 256, 0, stream>>>(tA, offs, ep, b3, out, n);
}

// Round 9
// 197.491 us; speedup vs baseline: 1.1899x; 1.1899x over previous
//
#include <hip/hip_runtime.h>
#include <hip/hip_bf16.h>
#include <hip/hip_fp16.h>

// ---------------------------------------------------------------------------
// GCN 3-layer forward.
//  - Layers 1-2 GEMM: bf16 MFMA (16x16x32), fp32 accum.
//  - Layer 3 GEMM: fp32 vector (error insurance on the output layer).
//  - Aggregation: CSR-by-dst gather of bf16 rows, fp32 accum, 2 nodes/wave.
//  - CSR build via RANK-FROM-HIST: k_hist's atomicAdd returns each edge's
//    rank within its dst row -> k_fill is atomic-free (coalesced reads +
//    one scatter store), single pass, no partitioning, no cursor array.
//  - Edge record: u32 {fp16 norm | u16 src}. Rows padded to x8, pad = 0.
//    Self-loop occupies reserved rank 0 (deg initialized to 1).
// ---------------------------------------------------------------------------

typedef __attribute__((ext_vector_type(8))) short s16x8;
typedef __attribute__((ext_vector_type(8))) unsigned short u16x8;
typedef __attribute__((ext_vector_type(4))) float f32x4;

__device__ __forceinline__ float bfu_lo(uint v) { return __uint_as_float(v << 16); }
__device__ __forceinline__ float bfu_hi(uint v) { return __uint_as_float(v & 0xffff0000u); }
__device__ __forceinline__ float dec_norm(uint m) {
    return __half2float(__ushort_as_half((ushort)(m >> 16)));
}
__device__ __forceinline__ ushort bf16_bits(float f) {
    union { __hip_bfloat16 h; ushort u; } x;
    x.h = __float2bfloat16(f);
    return x.u;
}

// ---------------- CSR build ----------------

__global__ void k_init(int* __restrict__ deg, int n,
                       uint4* __restrict__ ep4, int cap4) {
    int i = blockIdx.x * blockDim.x + threadIdx.x;
    if (i < n) deg[i] = 1;                       // slot 0 reserved: self-loop
    if (i < cap4) ep4[i] = make_uint4(0u, 0u, 0u, 0u);
}

// histogram + per-edge rank (the atomic's return value IS the CSR slot index)
__global__ void k_hist(const int* __restrict__ dst, int E,
                       int* __restrict__ deg, ushort* __restrict__ rank) {
    int e = blockIdx.x * blockDim.x + threadIdx.x;
    if (e < E) {
        int r = atomicAdd(&deg[dst[e]], 1);
        rank[e] = (ushort)r;                     // deg <= ~60 << 65536
    }
}

__global__ void k_scan_block(const int* __restrict__ deg, int* __restrict__ offs,
                             int* __restrict__ bsum, float* __restrict__ dinv, int n) {
    __shared__ int sm[256];
    int tid = threadIdx.x;
    int i = blockIdx.x * 256 + tid;
    int v = (i < n) ? deg[i] : 0;
    int pv = (i < n) ? ((v + 7) & ~7) : 0;   // pad rows to x8
    if (i < n) dinv[i] = rsqrtf((float)v);
    sm[tid] = pv;
    __syncthreads();
    for (int off = 1; off < 256; off <<= 1) {
        int t = (tid >= off) ? sm[tid - off] : 0;
        __syncthreads();
        sm[tid] += t;
        __syncthreads();
    }
    if (i < n) offs[i] = sm[tid] - pv;
    if (tid == 255) bsum[blockIdx.x] = sm[255];
}

__global__ void k_scan_bsum(int* __restrict__ bsum, int nb, int* __restrict__ offs, int n) {
    __shared__ int sm[256];
    int tid = threadIdx.x;
    int v = (tid < nb) ? bsum[tid] : 0;
    sm[tid] = v;
    __syncthreads();
    for (int off = 1; off < 256; off <<= 1) {
        int t = (tid >= off) ? sm[tid - off] : 0;
        __syncthreads();
        sm[tid] += t;
        __syncthreads();
    }
    if (tid < nb) bsum[tid] = sm[tid] - v;
    if (tid == 255) offs[n] = sm[255];
}

__global__ void k_add_bsum(int* __restrict__ offs, const int* __restrict__ bsum, int n) {
    int i = blockIdx.x * blockDim.x + threadIdx.x;
    if (i < n) offs[i] += bsum[i >> 8];
}

// atomic-free CSR fill: pos = offs[dst] + rank (self-loop -> rank 0).
__global__ __launch_bounds__(256) void k_fill(const int* __restrict__ src,
                                              const int* __restrict__ dst,
                                              const ushort* __restrict__ rank,
                                              int E, int n,
                                              const int* __restrict__ offs,
                                              const float* __restrict__ dinv,
                                              uint* __restrict__ ep) {
    int e = blockIdx.x * blockDim.x + threadIdx.x;
    int tot = E + n;
    if (e >= tot) return;
    int s, d, r;
    if (e < E) {
        s = src[e];
        d = dst[e];
        r = rank[e];
    } else {
        s = d = e - E;
        r = 0;
    }
    int pos = offs[d] + r;
    uint hb = (uint)__half_as_ushort(__float2half(dinv[s] * dinv[d]));
    ep[pos] = (hb << 16) | (uint)s;
}

// ---------------- W transpose+quantize (once per launch) ----------------
__global__ void k_transW(const float* __restrict__ W1, const float* __restrict__ W2,
                         ushort* __restrict__ Wt1, ushort* __restrict__ Wt2) {
    int i = blockIdx.x * 256 + threadIdx.x;
    if (i < 128 * 128) {
        int r = i >> 7, c = i & 127;
        Wt1[c * 128 + r] = bf16_bits(W1[i]);
        Wt2[c * 128 + r] = bf16_bits(W2[i]);
    }
}

// ---------------- MFMA GEMM (OUT=128): T = A @ W, bf16 in, bf16 out -------
template <bool ABF16>
__global__ __launch_bounds__(256) void k_gemm_mfma(const void* __restrict__ Ain,
                                                   const ushort* __restrict__ Wt,
                                                   __hip_bfloat16* __restrict__ T, int n) {
    __shared__ ushort As[64][136];
    __shared__ ushort Ws[128][136];
    const int tid = threadIdx.x;
    const int wave = tid >> 6, lane = tid & 63;
    const int m0 = blockIdx.x * 64;

#pragma unroll
    for (int it = 0; it < 8; ++it) {
        int idx = it * 256 + tid;
        int r = idx >> 4;
        int c8 = (idx & 15) << 3;
        *(u16x8*)&Ws[r][c8] = *(const u16x8*)(Wt + r * 128 + c8);
    }
    if constexpr (ABF16) {
        const ushort* A = (const ushort*)Ain;
#pragma unroll
        for (int it = 0; it < 4; ++it) {
            int idx = it * 256 + tid;
            int r = idx >> 4;
            int c8 = (idx & 15) << 3;
            u16x8 v = {0, 0, 0, 0, 0, 0, 0, 0};
            if (m0 + r < n) v = *(const u16x8*)(A + (size_t)(m0 + r) * 128 + c8);
            *(u16x8*)&As[r][c8] = v;
        }
    } else {
        const float* A = (const float*)Ain;
#pragma unroll
        for (int it = 0; it < 8; ++it) {
            int idx = it * 256 + tid;
            int r = idx >> 5;
            int c4 = (idx & 31) << 2;
            float4 v = make_float4(0.f, 0.f, 0.f, 0.f);
            if (m0 + r < n) v = *(const float4*)(A + (size_t)(m0 + r) * 128 + c4);
            As[r][c4 + 0] = bf16_bits(v.x);
            As[r][c4 + 1] = bf16_bits(v.y);
            As[r][c4 + 2] = bf16_bits(v.z);
            As[r][c4 + 3] = bf16_bits(v.w);
        }
    }
    __syncthreads();

    const int lrow = lane & 15;
    const int kgrp = lane >> 4;

    s16x8 a[4];
#pragma unroll
    for (int kk = 0; kk < 4; ++kk)
        a[kk] = *(const s16x8*)&As[wave * 16 + lrow][kk * 32 + kgrp * 8];

    f32x4 acc[8];
#pragma unroll
    for (int nt = 0; nt < 8; ++nt) {
        f32x4 c = {0.f, 0.f, 0.f, 0.f};
#pragma unroll
        for (int kk = 0; kk < 4; ++kk) {
            s16x8 b = *(const s16x8*)&Ws[nt * 16 + lrow][kk * 32 + kgrp * 8];
            c = __builtin_amdgcn_mfma_f32_16x16x32_bf16(a[kk], b, c, 0, 0, 0);
        }
        acc[nt] = c;
    }

    ushort* To = (ushort*)T;
#pragma unroll
    for (int j = 0; j < 4; ++j) {
        int row = m0 + wave * 16 + kgrp * 4 + j;
        if (row < n) {
#pragma unroll
            for (int nt = 0; nt < 8; ++nt)
                To[(size_t)row * 128 + nt * 16 + lrow] = bf16_bits(acc[nt][j]);
        }
    }
}

// ---------------- fp32 vector GEMM (OUT=64, layer 3), A bf16 --------------
__global__ __launch_bounds__(256) void k_gemm64(const ushort* __restrict__ Aq,
                                                const float* __restrict__ W,
                                                __hip_bfloat16* __restrict__ T, int n) {
    __shared__ float As[32][68];
    __shared__ float Bs[32][68];
    const int tid = threadIdx.x;
    const int tx = tid & 15, ty = tid >> 4;
    const int m0 = blockIdx.x * 64;

    float acc[4][4] = {};

    for (int k0 = 0; k0 < 128; k0 += 32) {
#pragma unroll
        for (int it = 0; it < 2; ++it) {
            int idx = it * 256 + tid;
            int r = idx >> 3;
            int c4 = (idx & 7) << 2;
            float4 v = make_float4(0.f, 0.f, 0.f, 0.f);
            if (m0 + r < n) {
                ushort4 u = *(const ushort4*)(Aq + (size_t)(m0 + r) * 128 + k0 + c4);
                v.x = __uint_as_float((uint)u.x << 16);
                v.y = __uint_as_float((uint)u.y << 16);
                v.z = __uint_as_float((uint)u.z << 16);
                v.w = __uint_as_float((uint)u.w << 16);
            }
            As[c4 + 0][r] = v.x;
            As[c4 + 1][r] = v.y;
            As[c4 + 2][r] = v.z;
            As[c4 + 3][r] = v.w;
        }
#pragma unroll
        for (int it = 0; it < 2; ++it) {
            int idx = it * 256 + tid;
            int kk = idx >> 4;
            int c4 = (idx & 15) << 2;
            *(float4*)&Bs[kk][c4] = *(const float4*)(W + (size_t)(k0 + kk) * 64 + c4);
        }
        __syncthreads();

#pragma unroll
        for (int k = 0; k < 32; ++k) {
            float4 a = *(const float4*)&As[k][ty * 4];
            float4 b0 = *(const float4*)&Bs[k][tx * 4];
            float av[4] = {a.x, a.y, a.z, a.w};
#pragma unroll
            for (int i = 0; i < 4; ++i) {
                acc[i][0] += av[i] * b0.x;
                acc[i][1] += av[i] * b0.y;
                acc[i][2] += av[i] * b0.z;
                acc[i][3] += av[i] * b0.w;
            }
        }
        __syncthreads();
    }

#pragma unroll
    for (int i = 0; i < 4; ++i) {
        int r = m0 + ty * 4 + i;
        if (r < n) {
            union { ushort h[4]; uint2 u; } p;
#pragma unroll
            for (int j = 0; j < 4; ++j) p.h[j] = bf16_bits(acc[i][j]);
            *(uint2*)((ushort*)T + (size_t)r * 64 + tx * 4) = p.u;
        }
    }
}

// ---------------- Aggregation: 2 nodes per wave, 16 gathers in flight -----
template <bool RELU>
__global__ __launch_bounds__(256) void k_agg128(const __hip_bfloat16* __restrict__ T,
                                                const int* __restrict__ offs,
                                                const uint* __restrict__ ep,
                                                const float* __restrict__ bias,
                                                uint* __restrict__ outq, int n) {
    int pr = blockIdx.x * 4 + (threadIdx.x >> 6);
    int lane = threadIdx.x & 63;
    int w0 = pr * 2;
    if (w0 >= n) return;
    int w1 = w0 + 1;
    bool has1 = (w1 < n);
    int eA = offs[w0], endA = offs[w0 + 1];
    int eB = has1 ? offs[w1] : 0;
    int endB = has1 ? offs[w1 + 1] : 0;

    const uint* Tl = (const uint*)T + lane;
    const uint4 z4 = make_uint4(0u, 0u, 0u, 0u);
    float a0 = 0.f, a1 = 0.f, c0 = 0.f, c1 = 0.f;

    uint4 mA0 = *(const uint4*)(ep + eA);
    uint4 mA1 = *(const uint4*)(ep + eA + 4);
    uint4 mB0 = z4, mB1 = z4;
    if (eB < endB) { mB0 = *(const uint4*)(ep + eB); mB1 = *(const uint4*)(ep + eB + 4); }

    for (;;) {
        uint rA0 = Tl[(size_t)(mA0.x & 0xffffu) * 64];
        uint rA1 = Tl[(size_t)(mA0.y & 0xffffu) * 64];
        uint rA2 = Tl[(size_t)(mA0.z & 0xffffu) * 64];
        uint rA3 = Tl[(size_t)(mA0.w & 0xffffu) * 64];
        uint rA4 = Tl[(size_t)(mA1.x & 0xffffu) * 64];
        uint rA5 = Tl[(size_t)(mA1.y & 0xffffu) * 64];
        uint rA6 = Tl[(size_t)(mA1.z & 0xffffu) * 64];
        uint rA7 = Tl[(size_t)(mA1.w & 0xffffu) * 64];
        uint rB0 = Tl[(size_t)(mB0.x & 0xffffu) * 64];
        uint rB1 = Tl[(size_t)(mB0.y & 0xffffu) * 64];
        uint rB2 = Tl[(size_t)(mB0.z & 0xffffu) * 64];
        uint rB3 = Tl[(size_t)(mB0.w & 0xffffu) * 64];
        uint rB4 = Tl[(size_t)(mB1.x & 0xffffu) * 64];
        uint rB5 = Tl[(size_t)(mB1.y & 0xffffu) * 64];
        uint rB6 = Tl[(size_t)(mB1.z & 0xffffu) * 64];
        uint rB7 = Tl[(size_t)(mB1.w & 0xffffu) * 64];
        float wA0 = dec_norm(mA0.x), wA1 = dec_norm(mA0.y);
        float wA2 = dec_norm(mA0.z), wA3 = dec_norm(mA0.w);
        float wA4 = dec_norm(mA1.x), wA5 = dec_norm(mA1.y);
        float wA6 = dec_norm(mA1.z), wA7 = dec_norm(mA1.w);
        float wB0 = dec_norm(mB0.x), wB1 = dec_norm(mB0.y);
        float wB2 = dec_norm(mB0.z), wB3 = dec_norm(mB0.w);
        float wB4 = dec_norm(mB1.x), wB5 = dec_norm(mB1.y);
        float wB6 = dec_norm(mB1.z), wB7 = dec_norm(mB1.w);
        eA += 8;
        eB += 8;
        bool moreA = (eA < endA), moreB = (eB < endB);
        if (moreA) { mA0 = *(const uint4*)(ep + eA); mA1 = *(const uint4*)(ep + eA + 4); }
        else       { mA0 = z4; mA1 = z4; }
        if (moreB) { mB0 = *(const uint4*)(ep + eB); mB1 = *(const uint4*)(ep + eB + 4); }
        else       { mB0 = z4; mB1 = z4; }
        a0 += wA0 * bfu_lo(rA0); a1 += wA0 * bfu_hi(rA0);
        a0 += wA1 * bfu_lo(rA1); a1 += wA1 * bfu_hi(rA1);
        a0 += wA2 * bfu_lo(rA2); a1 += wA2 * bfu_hi(rA2);
        a0 += wA3 * bfu_lo(rA3); a1 += wA3 * bfu_hi(rA3);
        a0 += wA4 * bfu_lo(rA4); a1 += wA4 * bfu_hi(rA4);
        a0 += wA5 * bfu_lo(rA5); a1 += wA5 * bfu_hi(rA5);
        a0 += wA6 * bfu_lo(rA6); a1 += wA6 * bfu_hi(rA6);
        a0 += wA7 * bfu_lo(rA7); a1 += wA7 * bfu_hi(rA7);
        c0 += wB0 * bfu_lo(rB0); c1 += wB0 * bfu_hi(rB0);
        c0 += wB1 * bfu_lo(rB1); c1 += wB1 * bfu_hi(rB1);
        c0 += wB2 * bfu_lo(rB2); c1 += wB2 * bfu_hi(rB2);
        c0 += wB3 * bfu_lo(rB3); c1 += wB3 * bfu_hi(rB3);
        c0 += wB4 * bfu_lo(rB4); c1 += wB4 * bfu_hi(rB4);
        c0 += wB5 * bfu_lo(rB5); c1 += wB5 * bfu_hi(rB5);
        c0 += wB6 * bfu_lo(rB6); c1 += wB6 * bfu_hi(rB6);
        c0 += wB7 * bfu_lo(rB7); c1 += wB7 * bfu_hi(rB7);
        if (!moreA && !moreB) break;
    }

    float2 b = *(const float2*)(bias + (lane << 1));
    a0 += b.x; a1 += b.y;
    if (RELU) { a0 = fmaxf(a0, 0.f); a1 = fmaxf(a1, 0.f); }
    outq[(size_t)w0 * 64 + lane] = ((uint)bf16_bits(a1) << 16) | (uint)bf16_bits(a0);
    if (has1) {
        c0 += b.x; c1 += b.y;
        if (RELU) { c0 = fmaxf(c0, 0.f); c1 = fmaxf(c1, 0.f); }
        outq[(size_t)w1 * 64 + lane] = ((uint)bf16_bits(c1) << 16) | (uint)bf16_bits(c0);
    }
}

__global__ __launch_bounds__(256) void k_agg64(const __hip_bfloat16* __restrict__ T,
                                               const int* __restrict__ offs,
                                               const uint* __restrict__ ep,
                                               const float* __restrict__ bias,
                                               float* __restrict__ out, int n) {
    int pr = blockIdx.x * 4 + (threadIdx.x >> 6);
    int lane = threadIdx.x & 63;
    int w0 = pr * 2;
    if (w0 >= n) return;
    int w1 = w0 + 1;
    bool has1 = (w1 < n);
    int eA = offs[w0], endA = offs[w0 + 1];
    int eB = has1 ? offs[w1] : 0;
    int endB = has1 ? offs[w1 + 1] : 0;

    const ushort* Tl = (const ushort*)T + lane;
    const uint4 z4 = make_uint4(0u, 0u, 0u, 0u);
    float a0 = 0.f, c0 = 0.f;

    uint4 mA0 = *(const uint4*)(ep + eA);
    uint4 mA1 = *(const uint4*)(ep + eA + 4);
    uint4 mB0 = z4, mB1 = z4;
    if (eB < endB) { mB0 = *(const uint4*)(ep + eB); mB1 = *(const uint4*)(ep + eB + 4); }

    for (;;) {
        float rA0 = __uint_as_float((uint)Tl[(size_t)(mA0.x & 0xffffu) * 64] << 16);
        float rA1 = __uint_as_float((uint)Tl[(size_t)(mA0.y & 0xffffu) * 64] << 16);
        float rA2 = __uint_as_float((uint)Tl[(size_t)(mA0.z & 0xffffu) * 64] << 16);
        float rA3 = __uint_as_float((uint)Tl[(size_t)(mA0.w & 0xffffu) * 64] << 16);
        float rA4 = __uint_as_float((uint)Tl[(size_t)(mA1.x & 0xffffu) * 64] << 16);
        float rA5 = __uint_as_float((uint)Tl[(size_t)(mA1.y & 0xffffu) * 64] << 16);
        float rA6 = __uint_as_float((uint)Tl[(size_t)(mA1.z & 0xffffu) * 64] << 16);
        float rA7 = __uint_as_float((uint)Tl[(size_t)(mA1.w & 0xffffu) * 64] << 16);
        float rB0 = __uint_as_float((uint)Tl[(size_t)(mB0.x & 0xffffu) * 64] << 16);
        float rB1 = __uint_as_float((uint)Tl[(size_t)(mB0.y & 0xffffu) * 64] << 16);
        float rB2 = __uint_as_float((uint)Tl[(size_t)(mB0.z & 0xffffu) * 64] << 16);
        float rB3 = __uint_as_float((uint)Tl[(size_t)(mB0.w & 0xffffu) * 64] << 16);
        float rB4 = __uint_as_float((uint)Tl[(size_t)(mB1.x & 0xffffu) * 64] << 16);
        float rB5 = __uint_as_float((uint)Tl[(size_t)(mB1.y & 0xffffu) * 64] << 16);
        float rB6 = __uint_as_float((uint)Tl[(size_t)(mB1.z & 0xffffu) * 64] << 16);
        float rB7 = __uint_as_float((uint)Tl[(size_t)(mB1.w & 0xffffu) * 64] << 16);
        float wA0 = dec_norm(mA0.x), wA1 = dec_norm(mA0.y);
        float wA2 = dec_norm(mA0.z), wA3 = dec_norm(mA0.w);
        float wA4 = dec_norm(mA1.x), wA5 = dec_norm(mA1.y);
        float wA6 = dec_norm(mA1.z), wA7 = dec_norm(mA1.w);
        float wB0 = dec_norm(mB0.x), wB1 = dec_norm(mB0.y);
        float wB2 = dec_norm(mB0.z), wB3 = dec_norm(mB0.w);
        float wB4 = dec_norm(mB1.x), wB5 = dec_norm(mB1.y);
        float wB6 = dec_norm(mB1.z), wB7 = dec_norm(mB1.w);
        eA += 8;
        eB += 8;
        bool moreA = (eA < endA), moreB = (eB < endB);
        if (moreA) { mA0 = *(const uint4*)(ep + eA); mA1 = *(const uint4*)(ep + eA + 4); }
        else       { mA0 = z4; mA1 = z4; }
        if (moreB) { mB0 = *(const uint4*)(ep + eB); mB1 = *(const uint4*)(ep + eB + 4); }
        else       { mB0 = z4; mB1 = z4; }
        a0 += wA0 * rA0 + wA1 * rA1 + wA2 * rA2 + wA3 * rA3;
        a0 += wA4 * rA4 + wA5 * rA5 + wA6 * rA6 + wA7 * rA7;
        c0 += wB0 * rB0 + wB1 * rB1 + wB2 * rB2 + wB3 * rB3;
        c0 += wB4 * rB4 + wB5 * rB5 + wB6 * rB6 + wB7 * rB7;
        if (!moreA && !moreB) break;
    }

    float bv = bias[lane];
    out[(size_t)w0 * 64 + lane] = a0 + bv;
    if (has1) out[(size_t)w1 * 64 + lane] = c0 + bv;
}

// ---------------------------------------------------------------------------

extern "C" void kernel_launch(void* const* d_in, const int* in_sizes, int n_in,
                              void* d_out, int out_size, void* d_ws, size_t ws_size,
                              hipStream_t stream) {
    const int n = in_sizes[0] / 128;   // 50000
    const int E = in_sizes[1] / 2;     // 800000

    const float* x  = (const float*)d_in[0];
    const int*   ei = (const int*)d_in[1];
    const float* W1 = (const float*)d_in[2];
    const float* b1 = (const float*)d_in[3];
    const float* W2 = (const float*)d_in[4];
    const float* b2 = (const float*)d_in[5];
    const float* W3 = (const float*)d_in[6];
    const float* b3 = (const float*)d_in[7];
    const int* src = ei;
    const int* dst = ei + E;
    float* out = (float*)d_out;

    const int cap = E + 8 * n;  // max padded slots

    char* w = (char*)d_ws;
    auto alloc = [&](size_t bytes) {
        char* p = w;
        w += (bytes + 255) & ~(size_t)255;
        return p;
    };
    int*    deg    = (int*)alloc((size_t)n * 4);
    int*    offs   = (int*)alloc((size_t)(n + 1) * 4);
    int*    bsum   = (int*)alloc(256 * 4);
    float*  dinv   = (float*)alloc((size_t)n * 4);
    ushort* rank   = (ushort*)alloc((size_t)E * 2);
    uint*   ep     = (uint*)alloc((size_t)cap * 4);
    __hip_bfloat16* tA = (__hip_bfloat16*)alloc((size_t)n * 128 * 2); // gathered t
    uint*   hB     = (uint*)alloc((size_t)n * 64 * 4);                // h packed bf16x2
    ushort* Wt1    = (ushort*)alloc(128 * 128 * 2);
    ushort* Wt2    = (ushort*)alloc(128 * 128 * 2);

    const int nb = (n + 255) / 256;

    // ---- CSR build + weight prep ----
    const int cap4 = (cap + 3) / 4;
    k_init<<<(cap4 + 255) / 256, 256, 0, stream>>>(deg, n, (uint4*)ep, cap4);
    k_transW<<<64, 256, 0, stream>>>(W1, W2, Wt1, Wt2);
    k_hist<<<(E + 255) / 256, 256, 0, stream>>>(dst, E, deg, rank);
    k_scan_block<<<nb, 256, 0, stream>>>(deg, offs, bsum, dinv, n);
    k_scan_bsum<<<1, 256, 0, stream>>>(bsum, nb, offs, n);
    k_add_bsum<<<nb, 256, 0, stream>>>(offs, bsum, n);
    k_fill<<<(E + n + 255) / 256, 256, 0, stream>>>(src, dst, rank, E, n, offs, dinv, ep);

    // ---- 3 GCN layers ----
    const int pair_blocks = ((n + 1) / 2 + 3) / 4;   // 2 nodes/wave, 4 waves/block
    const int gemm_blocks = (n + 63) / 64;

    k_gemm_mfma<false><<<gemm_blocks, 256, 0, stream>>>(x, Wt1, tA, n);
    k_agg128<true><<<pair_blocks, 256, 0, stream>>>(tA, offs, ep, b1, hB, n);

    k_gemm_mfma<true><<<gemm_blocks, 256, 0, stream>>>(hB, Wt2, tA, n);
    k_agg128<true><<<pair_blocks, 256, 0, stream>>>(tA, offs, ep, b2, hB, n);

    k_gemm64<<<gemm_blocks, 256, 0, stream>>>((const ushort*)hB, W3, tA, n);
    k_agg64<<<pair_blocks, 256, 0, stream>>>(tA, offs, ep, b3, out, n);
}